// Round 1
// baseline (1772.855 us; speedup 1.0000x reference)
//
#include <hip/hip_runtime.h>
#include <math.h>

#define N_NODES 100000
#define N_EDGES 1200000
#define N_GRAPHS 16
#define CH 64
#define HEADS 4
#define GL 6
#define IN_DIM 261
#define GDIM 24
#define LIN 32
#define LL 3
#define EPSN 1e-5f

__device__ __forceinline__ float gelu_exact(float x) {
  return 0.5f * x * (1.0f + erff(x * 0.70710678118654752440f));
}

__device__ __forceinline__ float ln32(float x, float w, float b) {
  // LayerNorm over groups of 32 lanes (xor masks < 32 stay within the group)
  float m = x;
  m += __shfl_xor(m, 1); m += __shfl_xor(m, 2); m += __shfl_xor(m, 4);
  m += __shfl_xor(m, 8); m += __shfl_xor(m, 16);
  m *= (1.0f / 32.0f);
  float d = x - m;
  float v = d * d;
  v += __shfl_xor(v, 1); v += __shfl_xor(v, 2); v += __shfl_xor(v, 4);
  v += __shfl_xor(v, 8); v += __shfl_xor(v, 16);
  v *= (1.0f / 32.0f);
  return d * rsqrtf(v + EPSN) * w + b;
}

// ---------------- setup: CSR build (sort edges by dst) ----------------
__global__ void k_count_deg(const int* __restrict__ dst, int* __restrict__ deg) {
  int e = blockIdx.x * 256 + threadIdx.x;
  if (e < N_EDGES) atomicAdd(&deg[dst[e]], 1);
}

__global__ void k_block_sums(const int* __restrict__ deg, int* __restrict__ bsum) {
  __shared__ int sh[256];
  int i = blockIdx.x * 256 + threadIdx.x;
  sh[threadIdx.x] = (i < N_NODES) ? deg[i] : 0;
  __syncthreads();
  for (int s = 128; s > 0; s >>= 1) {
    if (threadIdx.x < s) sh[threadIdx.x] += sh[threadIdx.x + s];
    __syncthreads();
  }
  if (threadIdx.x == 0) bsum[blockIdx.x] = sh[0];
}

__global__ void k_scan_bsums(int* __restrict__ bsum, int nb, int* __restrict__ off) {
  __shared__ int sh[512];
  int i = threadIdx.x;
  int v = (i < nb) ? bsum[i] : 0;
  sh[i] = v;
  __syncthreads();
  for (int s = 1; s < 512; s <<= 1) {
    int t = (i >= s) ? sh[i - s] : 0;
    __syncthreads();
    sh[i] += t;
    __syncthreads();
  }
  if (i < nb) bsum[i] = sh[i] - v;           // exclusive block prefix
  if (i == nb - 1) off[N_NODES] = sh[i];     // total == N_EDGES
}

__global__ void k_scan_final(const int* __restrict__ deg, const int* __restrict__ bsum,
                             int* __restrict__ off, int* __restrict__ cur) {
  __shared__ int sh[256];
  int i = blockIdx.x * 256 + threadIdx.x;
  int v = (i < N_NODES) ? deg[i] : 0;
  sh[threadIdx.x] = v;
  __syncthreads();
  for (int s = 1; s < 256; s <<= 1) {
    int t = (threadIdx.x >= s) ? sh[threadIdx.x - s] : 0;
    __syncthreads();
    sh[threadIdx.x] += t;
    __syncthreads();
  }
  if (i < N_NODES) {
    int ex = bsum[blockIdx.x] + sh[threadIdx.x] - v;
    off[i] = ex;
    cur[i] = ex;
  }
}

__global__ void k_scatter(const int* __restrict__ src, const int* __restrict__ dst,
                          int* __restrict__ cur, int* __restrict__ ssrc) {
  int e = blockIdx.x * 256 + threadIdx.x;
  if (e < N_EDGES) {
    int p = atomicAdd(&cur[dst[e]], 1);
    ssrc[p] = src[e];
  }
}

__global__ void k_graph_starts(const int* __restrict__ batch, int* __restrict__ gstart) {
  int g = threadIdx.x;
  if (g > N_GRAPHS) return;
  int lo = 0, hi = N_NODES;
  while (lo < hi) {
    int mid = (lo + hi) >> 1;
    if (batch[mid] < g) lo = mid + 1; else hi = mid;
  }
  gstart[g] = lo;
}

// ---------------- per-layer: GEMM (t = X @ W) + attention logits ----------------
__global__ __launch_bounds__(512) void k_gemm_logits(
    const float* __restrict__ Xin, int K, const float* __restrict__ W,
    const float* __restrict__ a_src, const float* __restrict__ a_dst,
    float* __restrict__ T, float* __restrict__ ES, float* __restrict__ ED) {
  __shared__ float sW[64 * 64];   // K-chunk x 64
  __shared__ float sX[32 * 64];   // 32 rows x K-chunk
  const int tid = threadIdx.x;
  const int col = tid & 63;
  const int rg = tid >> 6;        // 0..7, uniform per wave
  const long r0 = (long)blockIdx.x * 32;
  float acc[4] = {0.f, 0.f, 0.f, 0.f};
  for (int kc = 0; kc < K; kc += 64) {
    const int kl = min(64, K - kc);
    for (int i = tid; i < kl * 64; i += 512) sW[i] = W[(long)kc * 64 + i];
    const int nx = 32 * kl;
    for (int i = tid; i < nx; i += 512) {
      int rr = i / kl, cc = i - rr * kl;
      sX[rr * 64 + cc] = Xin[(r0 + rr) * (long)K + kc + cc];
    }
    __syncthreads();
    #pragma unroll 4
    for (int k = 0; k < kl; ++k) {
      float w = sW[k * 64 + col];
      #pragma unroll
      for (int i = 0; i < 4; ++i)
        acc[i] = fmaf(sX[(rg * 4 + i) * 64 + k], w, acc[i]);
    }
    __syncthreads();
  }
  const float as = a_src[col], ad = a_dst[col];
  #pragma unroll
  for (int i = 0; i < 4; ++i) {
    const long row = r0 + rg * 4 + i;
    T[row * 64 + col] = acc[i];
    float vs = acc[i] * as;
    float vd = acc[i] * ad;
    vs += __shfl_xor(vs, 1); vs += __shfl_xor(vs, 2); vs += __shfl_xor(vs, 4); vs += __shfl_xor(vs, 8);
    vd += __shfl_xor(vd, 1); vd += __shfl_xor(vd, 2); vd += __shfl_xor(vd, 4); vd += __shfl_xor(vd, 8);
    if ((col & 15) == 0) {
      ES[row * 4 + (col >> 4)] = vs;
      ED[row * 4 + (col >> 4)] = vd;
    }
  }
}

// ---------------- per-layer: edge softmax + aggregate (wave per node) ----------------
__global__ __launch_bounds__(256) void k_edge_agg(
    const float* __restrict__ T, const float* __restrict__ ES, const float* __restrict__ ED,
    const int* __restrict__ off, const int* __restrict__ ssrc,
    const float* __restrict__ bias, float* __restrict__ F) {
  const int lane = threadIdx.x & 63;
  const int n = blockIdx.x * 4 + (threadIdx.x >> 6);
  if (n >= N_NODES) return;
  const int e0 = off[n];
  const int ec = off[n + 1] - e0;
  const int hd = lane & 3;    // phase-A head (lane = edge*4 + head)
  const int qh = lane >> 4;   // phase-B head (lane = channel)
  const float ed_h = ED[n * 4 + hd];
  // self-loop logit initializes the online softmax
  float x0 = ES[n * 4 + hd] + ed_h;
  x0 = x0 > 0.f ? x0 : 0.2f * x0;
  float m_run = x0;
  float s_run = 1.0f;                       // exp(self - m) = 1
  float acc = T[(long)n * 64 + lane];       // self message, weight 1 (rescaled later)
  for (int base = 0; base < ec; base += 16) {
    const int eidx = base + (lane >> 2);
    const bool valid = eidx < ec;
    const int sv = valid ? ssrc[e0 + eidx] : 0;
    float logit = -1e30f;
    if (valid) {
      float v = ES[sv * 4 + hd] + ed_h;
      logit = v > 0.f ? v : 0.2f * v;
    }
    // chunk max per head (reduce over lanes with equal lane&3)
    float cm = logit;
    cm = fmaxf(cm, __shfl_xor(cm, 4));
    cm = fmaxf(cm, __shfl_xor(cm, 8));
    cm = fmaxf(cm, __shfl_xor(cm, 16));
    cm = fmaxf(cm, __shfl_xor(cm, 32));
    const float new_m = fmaxf(m_run, cm);
    const float scale = __expf(m_run - new_m);
    const float p = valid ? __expf(logit - new_m) : 0.f;
    float ps = p;
    ps += __shfl_xor(ps, 4); ps += __shfl_xor(ps, 8);
    ps += __shfl_xor(ps, 16); ps += __shfl_xor(ps, 32);
    s_run = fmaf(s_run, scale, ps);
    m_run = new_m;
    acc *= __shfl(scale, qh);               // rescale accumulator for my channel's head
    const int ce = min(16, ec - base);
    for (int e = 0; e < ce; ++e) {
      const float a = __shfl(p, (e << 2) | qh);
      const int srow = __shfl(sv, e << 2);
      acc = fmaf(a, T[(long)srow * 64 + lane], acc);
    }
  }
  const float s_q = __shfl(s_run, qh);
  const float o = acc / (s_q + 1e-16f) + bias[lane];
  F[(long)n * 64 + lane] = gelu_exact(o);
}

// ---------------- GraphNorm: per-graph moments, stats, normalize+residual ----------------
__global__ void k_graph_moments(const float* __restrict__ F, const int* __restrict__ gstart,
                                float* __restrict__ S, float* __restrict__ SQ) {
  const int g = blockIdx.x;
  const int s0 = gstart[g];
  const int rows = gstart[g + 1] - s0;
  const int lane = threadIdx.x & 63;
  const int w = threadIdx.x >> 6;
  float sum = 0.f, sq = 0.f;
  for (int r = blockIdx.y * 4 + w; r < rows; r += gridDim.y * 4) {
    float v = F[(long)(s0 + r) * 64 + lane];
    sum += v;
    sq = fmaf(v, v, sq);
  }
  __shared__ float ls[4][64];
  __shared__ float lq[4][64];
  ls[w][lane] = sum;
  lq[w][lane] = sq;
  __syncthreads();
  if (w == 0) {
    float a = ls[0][lane] + ls[1][lane] + ls[2][lane] + ls[3][lane];
    float b = lq[0][lane] + lq[1][lane] + lq[2][lane] + lq[3][lane];
    atomicAdd(&S[g * 64 + lane], a);
    atomicAdd(&SQ[g * 64 + lane], b);
  }
}

__global__ void k_graph_stats(const float* __restrict__ S, const float* __restrict__ SQ,
                              const int* __restrict__ gstart, const float* __restrict__ ms,
                              float* __restrict__ MM, float* __restrict__ IS) {
  const int i = threadIdx.x;  // 1024 = 16*64
  const int g = i >> 6, c = i & 63;
  const float cnt = fmaxf((float)(gstart[g + 1] - gstart[g]), 1.0f);
  const float mean = S[i] / cnt;
  const float mm = mean * ms[c];
  // var = E[(x - mm)^2] = E[x^2] - 2*mm*E[x] + mm^2
  float var = SQ[i] / cnt - 2.f * mm * mean + mm * mm;
  MM[i] = mm;
  IS[i] = rsqrtf(fmaxf(var, 0.f) + EPSN);
}

__global__ void k_norm_res(const float* __restrict__ F, const int* __restrict__ batch,
                           const float* __restrict__ MM, const float* __restrict__ IS,
                           const float* __restrict__ w, const float* __restrict__ b,
                           float* __restrict__ X, int residual) {
  const long i = (long)blockIdx.x * 256 + threadIdx.x;
  const int n = (int)(i >> 6), c = (int)(i & 63);
  const int g = batch[n];
  const float o = F[i] - MM[g * 64 + c];
  const float y = fmaf(w[c] * o, IS[g * 64 + c], b[c]);
  X[i] = residual ? (y + X[i]) : y;
}

// ---------------- pooled MLP head (one block) ----------------
__global__ __launch_bounds__(512) void k_mlp(
    const float* __restrict__ psum, const int* __restrict__ gstart, const float* __restrict__ gf,
    const float* __restrict__ W0, const float* __restrict__ b0,
    const float* __restrict__ lw0, const float* __restrict__ lb0,
    const float* __restrict__ Wg, const float* __restrict__ bg,
    const float* __restrict__ lwg, const float* __restrict__ lbg,
    const float* __restrict__ hW, const float* __restrict__ hb,
    float* __restrict__ out) {
  __shared__ float P[16][88];
  __shared__ float Z[16][32];
  const int tid = threadIdx.x;
  for (int i = tid; i < 16 * 88; i += 512) {
    int g = i / 88, c = i - g * 88;
    float v;
    if (c < 64) {
      float cnt = fmaxf((float)(gstart[g + 1] - gstart[g]), 1.0f);
      v = psum[g * 64 + c] / cnt;
    } else {
      v = gf[g * GDIM + (c - 64)];
    }
    P[g][c] = v;
  }
  __syncthreads();
  const int g = tid >> 5, c = tid & 31;
  float acc = b0[c];
  for (int k = 0; k < 88; ++k) acc = fmaf(P[g][k], W0[k * 32 + c], acc);
  float z = ln32(gelu_exact(acc), lw0[c], lb0[c]);
  for (int l = 0; l < LL; ++l) {
    Z[g][c] = z;
    __syncthreads();
    float a2 = bg[l * 32 + c];
    const float* Wl = Wg + l * 32 * 32;
    for (int k = 0; k < 32; ++k) a2 = fmaf(Z[g][k], Wl[k * 32 + c], a2);
    __syncthreads();
    z = ln32(gelu_exact(a2), lwg[l * 32 + c], lbg[l * 32 + c]) + z;
  }
  Z[g][c] = z * hW[c];
  __syncthreads();
  if (c == 0) {
    float s = 0.f;
    for (int k = 0; k < 32; ++k) s += Z[g][k];
    out[g] = s + hb[0];
  }
}

extern "C" void kernel_launch(void* const* d_in, const int* in_sizes, int n_in,
                              void* d_out, int out_size, void* d_ws, size_t ws_size,
                              hipStream_t stream) {
  const float* x   = (const float*)d_in[0];
  const int*   ei  = (const int*)d_in[1];
  const int* batch = (const int*)d_in[2];
  const float* gf  = (const float*)d_in[3];
  const float* W0  = (const float*)d_in[4];
  const float* as0 = (const float*)d_in[5];
  const float* ad0 = (const float*)d_in[6];
  const float* b0  = (const float*)d_in[7];
  const float* gw0 = (const float*)d_in[8];
  const float* gb0 = (const float*)d_in[9];
  const float* gm0 = (const float*)d_in[10];
  const float* Wg  = (const float*)d_in[11];
  const float* asg = (const float*)d_in[12];
  const float* adg = (const float*)d_in[13];
  const float* bg  = (const float*)d_in[14];
  const float* gwg = (const float*)d_in[15];
  const float* gbg = (const float*)d_in[16];
  const float* gmg = (const float*)d_in[17];
  const float* mW0 = (const float*)d_in[18];
  const float* mb0 = (const float*)d_in[19];
  const float* lw0 = (const float*)d_in[20];
  const float* lb0 = (const float*)d_in[21];
  const float* mWg = (const float*)d_in[22];
  const float* mbg = (const float*)d_in[23];
  const float* lwg = (const float*)d_in[24];
  const float* lbg = (const float*)d_in[25];
  const float* hW  = (const float*)d_in[26];
  const float* hb  = (const float*)d_in[27];
  float* out = (float*)d_out;
  const int* src = ei;
  const int* dst = ei + N_EDGES;

  char* p = (char*)d_ws;
  auto alloc = [&](size_t bytes) {
    char* r = p;
    p += (bytes + 255) & ~(size_t)255;
    return (void*)r;
  };
  float* X  = (float*)alloc((size_t)N_NODES * 64 * 4);
  float* T  = (float*)alloc((size_t)N_NODES * 64 * 4);
  float* F  = (float*)alloc((size_t)N_NODES * 64 * 4);
  float* ES = (float*)alloc((size_t)N_NODES * 4 * 4);
  float* ED = (float*)alloc((size_t)N_NODES * 4 * 4);
  int* ssrc = (int*)alloc((size_t)N_EDGES * 4);
  int* deg  = (int*)alloc((size_t)N_NODES * 4);
  int* off  = (int*)alloc((size_t)(N_NODES + 1) * 4);
  int* cur  = (int*)alloc((size_t)N_NODES * 4);
  int* bsum = (int*)alloc(4096);
  int* gstart = (int*)alloc((N_GRAPHS + 1) * 4);
  float* S  = (float*)alloc(N_GRAPHS * 64 * 4);   // 4096B, SQ directly follows
  float* SQ = (float*)alloc(N_GRAPHS * 64 * 4);
  float* MM = (float*)alloc(N_GRAPHS * 64 * 4);
  float* IS = (float*)alloc(N_GRAPHS * 64 * 4);
  (void)ws_size; (void)in_sizes; (void)n_in; (void)out_size;

  const int NB = (N_NODES + 255) / 256;  // 391
  hipMemsetAsync(deg, 0, (size_t)N_NODES * 4, stream);
  k_count_deg<<<(N_EDGES + 255) / 256, 256, 0, stream>>>(dst, deg);
  k_block_sums<<<NB, 256, 0, stream>>>(deg, bsum);
  k_scan_bsums<<<1, 512, 0, stream>>>(bsum, NB, off);
  k_scan_final<<<NB, 256, 0, stream>>>(deg, bsum, off, cur);
  k_scatter<<<(N_EDGES + 255) / 256, 256, 0, stream>>>(src, dst, cur, ssrc);
  k_graph_starts<<<1, 32, 0, stream>>>(batch, gstart);

  for (int l = 0; l < 1 + GL; ++l) {
    const float* Xin = (l == 0) ? x : X;
    const int K = (l == 0) ? IN_DIM : 64;
    const float* Wl  = (l == 0) ? W0  : (Wg  + (size_t)(l - 1) * 64 * 64);
    const float* asl = (l == 0) ? as0 : (asg + (size_t)(l - 1) * 64);
    const float* adl = (l == 0) ? ad0 : (adg + (size_t)(l - 1) * 64);
    const float* bl  = (l == 0) ? b0  : (bg  + (size_t)(l - 1) * 64);
    const float* gwl = (l == 0) ? gw0 : (gwg + (size_t)(l - 1) * 64);
    const float* gbl = (l == 0) ? gb0 : (gbg + (size_t)(l - 1) * 64);
    const float* gml = (l == 0) ? gm0 : (gmg + (size_t)(l - 1) * 64);
    k_gemm_logits<<<N_NODES / 32, 512, 0, stream>>>(Xin, K, Wl, asl, adl, T, ES, ED);
    k_edge_agg<<<N_NODES / 4, 256, 0, stream>>>(T, ES, ED, off, ssrc, bl, F);
    hipMemsetAsync(S, 0, (size_t)N_GRAPHS * 64 * 4 * 2, stream);  // S and SQ contiguous
    k_graph_moments<<<dim3(N_GRAPHS, 8), 256, 0, stream>>>(F, gstart, S, SQ);
    k_graph_stats<<<1, 1024, 0, stream>>>(S, SQ, gstart, gml, MM, IS);
    k_norm_res<<<(N_NODES * 64) / 256, 256, 0, stream>>>(F, batch, MM, IS, gwl, gbl, X, l > 0);
  }

  // global mean pool + MLP head
  hipMemsetAsync(S, 0, (size_t)N_GRAPHS * 64 * 4 * 2, stream);
  k_graph_moments<<<dim3(N_GRAPHS, 8), 256, 0, stream>>>(X, gstart, S, SQ);
  k_mlp<<<1, 512, 0, stream>>>(S, gstart, gf, mW0, mb0, lw0, lb0,
                               mWg, mbg, lwg, lbg, hW, hb, out);
}

// Round 2
// 1600.826 us; speedup vs baseline: 1.1075x; 1.1075x over previous
//
#include <hip/hip_runtime.h>
#include <math.h>

#define N_NODES 100000
#define N_EDGES 1200000
#define N_GRAPHS 16
#define CH 64
#define HEADS 4
#define GL 6
#define IN_DIM 261
#define GDIM 24
#define LIN 32
#define LL 3
#define EPSN 1e-5f

__device__ __forceinline__ float gelu_exact(float x) {
  return 0.5f * x * (1.0f + erff(x * 0.70710678118654752440f));
}

__device__ __forceinline__ float ln32(float x, float w, float b) {
  float m = x;
  m += __shfl_xor(m, 1); m += __shfl_xor(m, 2); m += __shfl_xor(m, 4);
  m += __shfl_xor(m, 8); m += __shfl_xor(m, 16);
  m *= (1.0f / 32.0f);
  float d = x - m;
  float v = d * d;
  v += __shfl_xor(v, 1); v += __shfl_xor(v, 2); v += __shfl_xor(v, 4);
  v += __shfl_xor(v, 8); v += __shfl_xor(v, 16);
  v *= (1.0f / 32.0f);
  return d * rsqrtf(v + EPSN) * w + b;
}

// ---------------- setup: CSR build (sort edges by dst) ----------------
__global__ void k_count_deg(const int* __restrict__ dst, int* __restrict__ deg) {
  int e = blockIdx.x * 256 + threadIdx.x;
  if (e < N_EDGES) atomicAdd(&deg[dst[e]], 1);
}

__global__ void k_block_sums(const int* __restrict__ deg, int* __restrict__ bsum) {
  __shared__ int sh[256];
  int i = blockIdx.x * 256 + threadIdx.x;
  sh[threadIdx.x] = (i < N_NODES) ? deg[i] : 0;
  __syncthreads();
  for (int s = 128; s > 0; s >>= 1) {
    if (threadIdx.x < s) sh[threadIdx.x] += sh[threadIdx.x + s];
    __syncthreads();
  }
  if (threadIdx.x == 0) bsum[blockIdx.x] = sh[0];
}

__global__ void k_scan_bsums(int* __restrict__ bsum, int nb, int* __restrict__ off) {
  __shared__ int sh[512];
  int i = threadIdx.x;
  int v = (i < nb) ? bsum[i] : 0;
  sh[i] = v;
  __syncthreads();
  for (int s = 1; s < 512; s <<= 1) {
    int t = (i >= s) ? sh[i - s] : 0;
    __syncthreads();
    sh[i] += t;
    __syncthreads();
  }
  if (i < nb) bsum[i] = sh[i] - v;
  if (i == nb - 1) off[N_NODES] = sh[i];
}

__global__ void k_scan_final(const int* __restrict__ deg, const int* __restrict__ bsum,
                             int* __restrict__ off, int* __restrict__ cur) {
  __shared__ int sh[256];
  int i = blockIdx.x * 256 + threadIdx.x;
  int v = (i < N_NODES) ? deg[i] : 0;
  sh[threadIdx.x] = v;
  __syncthreads();
  for (int s = 1; s < 256; s <<= 1) {
    int t = (threadIdx.x >= s) ? sh[threadIdx.x - s] : 0;
    __syncthreads();
    sh[threadIdx.x] += t;
    __syncthreads();
  }
  if (i < N_NODES) {
    int ex = bsum[blockIdx.x] + sh[threadIdx.x] - v;
    off[i] = ex;
    cur[i] = ex;
  }
}

__global__ void k_scatter(const int* __restrict__ src, const int* __restrict__ dst,
                          int* __restrict__ cur, int* __restrict__ ssrc) {
  int e = blockIdx.x * 256 + threadIdx.x;
  if (e < N_EDGES) {
    int p = atomicAdd(&cur[dst[e]], 1);
    ssrc[p] = src[e];
  }
}

__global__ void k_graph_starts(const int* __restrict__ batch, int* __restrict__ gstart) {
  int g = threadIdx.x;
  if (g > N_GRAPHS) return;
  int lo = 0, hi = N_NODES;
  while (lo < hi) {
    int mid = (lo + hi) >> 1;
    if (batch[mid] < g) lo = mid + 1; else hi = mid;
  }
  gstart[g] = lo;
}

// ---------------- per-layer: GEMM (t = X @ W) + attention logits ----------------
// 128 threads, tile 128 rows x 64 cols, per-thread 8x8 (two 4-col islands 32 apart).
__global__ __launch_bounds__(128) void k_gemm_logits(
    const float* __restrict__ Xin, int K, const float* __restrict__ W,
    const float* __restrict__ a_src, const float* __restrict__ a_dst,
    float* __restrict__ T, float* __restrict__ ES, float* __restrict__ ED) {
  __shared__ float sXt[64][132];  // [k][row], stride 132: 16B-aligned rows, 2-way reads
  __shared__ float sW[64][68];    // [k][col]
  const int tid = threadIdx.x;
  const int rg = tid >> 3;        // 0..15 -> rows rg*8..+7
  const int cg = tid & 7;         // 0..7  -> cols cg*4..+3 and 32+cg*4..+3
  const long r0 = (long)blockIdx.x * 128;
  float acc[8][8];
  #pragma unroll
  for (int i = 0; i < 8; ++i)
    #pragma unroll
    for (int j = 0; j < 8; ++j) acc[i][j] = 0.f;

  for (int kc = 0; kc < K; kc += 64) {
    const int kl = min(64, K - kc);
    // --- stage W chunk [kl][64] row-major ---
    for (int i = tid; i < kl * 16; i += 128) {
      int k = i >> 4, c4 = (i & 15) << 2;
      float4 v = *(const float4*)(W + (size_t)(kc + k) * 64 + c4);
      *(float4*)&sW[k][c4] = v;
    }
    // --- stage X^T chunk ---
    if (K == 64) {
      // 4x4 register micro-transpose, all b128, conflict-free
      #pragma unroll
      for (int m = 0; m < 4; ++m) {
        int tau = tid + (m << 7);
        int k4 = (tau & 15) << 2;
        int r4 = (tau >> 4) << 2;
        float4 a0, a1, a2, a3;
        long rr = r0 + r4;
        const float4 z4 = make_float4(0.f, 0.f, 0.f, 0.f);
        a0 = (rr + 0 < N_NODES) ? *(const float4*)(Xin + (rr + 0) * 64 + k4) : z4;
        a1 = (rr + 1 < N_NODES) ? *(const float4*)(Xin + (rr + 1) * 64 + k4) : z4;
        a2 = (rr + 2 < N_NODES) ? *(const float4*)(Xin + (rr + 2) * 64 + k4) : z4;
        a3 = (rr + 3 < N_NODES) ? *(const float4*)(Xin + (rr + 3) * 64 + k4) : z4;
        *(float4*)&sXt[k4 + 0][r4] = make_float4(a0.x, a1.x, a2.x, a3.x);
        *(float4*)&sXt[k4 + 1][r4] = make_float4(a0.y, a1.y, a2.y, a3.y);
        *(float4*)&sXt[k4 + 2][r4] = make_float4(a0.z, a1.z, a2.z, a3.z);
        *(float4*)&sXt[k4 + 3][r4] = make_float4(a0.w, a1.w, a2.w, a3.w);
      }
    } else {
      // generic scalar path (layer 0, K=261): coalesced global, 8-way LDS write (ok, once)
      for (int i = tid; i < 128 * 64; i += 128) {
        int r = i >> 6, k = i & 63;
        long rr = r0 + r;
        float v = (k < kl && rr < N_NODES) ? Xin[rr * (long)K + kc + k] : 0.f;
        sXt[k][r] = v;
      }
    }
    __syncthreads();
    // --- FMA: 64 per k from 4 b128 reads ---
    #pragma unroll 2
    for (int k = 0; k < kl; ++k) {
      float4 x0 = *(const float4*)&sXt[k][rg * 8];
      float4 x1 = *(const float4*)&sXt[k][rg * 8 + 4];
      float4 w0 = *(const float4*)&sW[k][cg * 4];
      float4 w1 = *(const float4*)&sW[k][cg * 4 + 32];
      float xr[8] = {x0.x, x0.y, x0.z, x0.w, x1.x, x1.y, x1.z, x1.w};
      float wr[8] = {w0.x, w0.y, w0.z, w0.w, w1.x, w1.y, w1.z, w1.w};
      #pragma unroll
      for (int i = 0; i < 8; ++i)
        #pragma unroll
        for (int j = 0; j < 8; ++j)
          acc[i][j] = fmaf(xr[i], wr[j], acc[i][j]);
    }
    __syncthreads();
  }

  // --- epilogue: store T, per-head logit partial sums ---
  const int cA = cg * 4;          // island A cols, head hA
  const int cB = cg * 4 + 32;     // island B cols, head hB
  const int hA = cg >> 2;         // 0 or 1
  const int hB = hA + 2;          // 2 or 3
  float asA[4], adA[4], asB[4], adB[4];
  #pragma unroll
  for (int j = 0; j < 4; ++j) {
    asA[j] = a_src[cA + j]; adA[j] = a_dst[cA + j];
    asB[j] = a_src[cB + j]; adB[j] = a_dst[cB + j];
  }
  #pragma unroll
  for (int i = 0; i < 8; ++i) {
    const long row = r0 + rg * 8 + i;
    if (row >= N_NODES) continue;
    *(float4*)(T + row * 64 + cA) = make_float4(acc[i][0], acc[i][1], acc[i][2], acc[i][3]);
    *(float4*)(T + row * 64 + cB) = make_float4(acc[i][4], acc[i][5], acc[i][6], acc[i][7]);
    float vsA = 0.f, vdA = 0.f, vsB = 0.f, vdB = 0.f;
    #pragma unroll
    for (int j = 0; j < 4; ++j) {
      vsA = fmaf(acc[i][j], asA[j], vsA);
      vdA = fmaf(acc[i][j], adA[j], vdA);
      vsB = fmaf(acc[i][4 + j], asB[j], vsB);
      vdB = fmaf(acc[i][4 + j], adB[j], vdB);
    }
    vsA += __shfl_xor(vsA, 1); vsA += __shfl_xor(vsA, 2);
    vdA += __shfl_xor(vdA, 1); vdA += __shfl_xor(vdA, 2);
    vsB += __shfl_xor(vsB, 1); vsB += __shfl_xor(vsB, 2);
    vdB += __shfl_xor(vdB, 1); vdB += __shfl_xor(vdB, 2);
    if ((cg & 3) == 0) {
      ES[row * 4 + hA] = vsA; ED[row * 4 + hA] = vdA;
      ES[row * 4 + hB] = vsB; ED[row * 4 + hB] = vdB;
    }
  }
}

// ---------------- per-layer: edge softmax + aggregate (wave per node) ----------------
__global__ __launch_bounds__(256) void k_edge_agg(
    const float* __restrict__ T, const float* __restrict__ ES, const float* __restrict__ ED,
    const int* __restrict__ off, const int* __restrict__ ssrc,
    const float* __restrict__ bias, float* __restrict__ F) {
  const int lane = threadIdx.x & 63;
  const int n = blockIdx.x * 4 + (threadIdx.x >> 6);
  if (n >= N_NODES) return;
  const int e0 = off[n];
  const int ec = off[n + 1] - e0;
  const int hd = lane & 3;    // phase-A head (lane = edge*4 + head)
  const int qh = lane >> 4;   // phase-B head (lane = channel)
  const float ed_h = ED[n * 4 + hd];
  float x0 = ES[n * 4 + hd] + ed_h;
  x0 = fmaxf(x0, 0.2f * x0);                 // leaky_relu
  float m_run = x0;
  float s_run = 1.0f;
  const float* Tl = T + lane;
  float acc = Tl[(long)n * 64];              // self message
  for (int base = 0; base < ec; base += 16) {
    const int eidx = base + (lane >> 2);
    const bool valid = eidx < ec;
    const int sv = valid ? ssrc[e0 + eidx] : n;
    float v = ES[sv * 4 + hd] + ed_h;
    float logit = valid ? fmaxf(v, 0.2f * v) : -1e30f;
    float cm = logit;
    cm = fmaxf(cm, __shfl_xor(cm, 4));
    cm = fmaxf(cm, __shfl_xor(cm, 8));
    cm = fmaxf(cm, __shfl_xor(cm, 16));
    cm = fmaxf(cm, __shfl_xor(cm, 32));
    const float new_m = fmaxf(m_run, cm);
    const float scale = __expf(m_run - new_m);
    const float p = valid ? __expf(logit - new_m) : 0.f;
    float ps = p;
    ps += __shfl_xor(ps, 4); ps += __shfl_xor(ps, 8);
    ps += __shfl_xor(ps, 16); ps += __shfl_xor(ps, 32);
    s_run = fmaf(s_run, scale, ps);
    m_run = new_m;
    acc *= __shfl(scale, qh);
    int rows[16];
    float al[16], tv[16];
    #pragma unroll
    for (int e = 0; e < 16; ++e) rows[e] = __shfl(sv, e << 2);
    #pragma unroll
    for (int e = 0; e < 16; ++e) al[e] = __shfl(p, (e << 2) | qh);
    #pragma unroll
    for (int e = 0; e < 16; ++e) tv[e] = Tl[(long)rows[e] * 64];
    #pragma unroll
    for (int e = 0; e < 16; ++e) acc = fmaf(al[e], tv[e], acc);
  }
  const float s_q = __shfl(s_run, qh);
  const float o = acc / (s_q + 1e-16f) + bias[lane];
  F[(long)n * 64 + lane] = gelu_exact(o);
}

// ---------------- GraphNorm ----------------
__global__ void k_graph_moments(const float* __restrict__ F, const int* __restrict__ gstart,
                                float* __restrict__ S, float* __restrict__ SQ) {
  const int g = blockIdx.x;
  const int s0 = gstart[g];
  const int rows = gstart[g + 1] - s0;
  const int lane = threadIdx.x & 63;
  const int w = threadIdx.x >> 6;
  float sum = 0.f, sq = 0.f;
  for (int r = blockIdx.y * 4 + w; r < rows; r += gridDim.y * 4) {
    float v = F[(long)(s0 + r) * 64 + lane];
    sum += v;
    sq = fmaf(v, v, sq);
  }
  __shared__ float ls[4][64];
  __shared__ float lq[4][64];
  ls[w][lane] = sum;
  lq[w][lane] = sq;
  __syncthreads();
  if (w == 0) {
    float a = ls[0][lane] + ls[1][lane] + ls[2][lane] + ls[3][lane];
    float b = lq[0][lane] + lq[1][lane] + lq[2][lane] + lq[3][lane];
    atomicAdd(&S[g * 64 + lane], a);
    atomicAdd(&SQ[g * 64 + lane], b);
  }
}

__global__ void k_graph_stats(const float* __restrict__ S, const float* __restrict__ SQ,
                              const int* __restrict__ gstart, const float* __restrict__ ms,
                              float* __restrict__ MM, float* __restrict__ IS) {
  const int i = threadIdx.x;
  const int g = i >> 6, c = i & 63;
  const float cnt = fmaxf((float)(gstart[g + 1] - gstart[g]), 1.0f);
  const float mean = S[i] / cnt;
  const float mm = mean * ms[c];
  float var = SQ[i] / cnt - 2.f * mm * mean + mm * mm;
  MM[i] = mm;
  IS[i] = rsqrtf(fmaxf(var, 0.f) + EPSN);
}

__global__ void k_norm_res(const float* __restrict__ F, const int* __restrict__ batch,
                           const float* __restrict__ MM, const float* __restrict__ IS,
                           const float* __restrict__ w, const float* __restrict__ b,
                           float* __restrict__ X, int residual) {
  const long i4 = (long)blockIdx.x * 256 + threadIdx.x;   // float4 index
  const int n = (int)(i4 >> 4);
  const int c4 = (int)(i4 & 15) << 2;
  const int g = batch[n];
  float4 f = *(const float4*)(F + i4 * 4);
  float4 mm = *(const float4*)(MM + g * 64 + c4);
  float4 is = *(const float4*)(IS + g * 64 + c4);
  float4 wv = *(const float4*)(w + c4);
  float4 bv = *(const float4*)(b + c4);
  float4 y;
  y.x = fmaf(wv.x * (f.x - mm.x), is.x, bv.x);
  y.y = fmaf(wv.y * (f.y - mm.y), is.y, bv.y);
  y.z = fmaf(wv.z * (f.z - mm.z), is.z, bv.z);
  y.w = fmaf(wv.w * (f.w - mm.w), is.w, bv.w);
  float4* xp = (float4*)(X + i4 * 4);
  if (residual) {
    float4 xo = *xp;
    y.x += xo.x; y.y += xo.y; y.z += xo.z; y.w += xo.w;
  }
  *xp = y;
}

// ---------------- pooled MLP head (one block) ----------------
__global__ __launch_bounds__(512) void k_mlp(
    const float* __restrict__ psum, const int* __restrict__ gstart, const float* __restrict__ gf,
    const float* __restrict__ W0, const float* __restrict__ b0,
    const float* __restrict__ lw0, const float* __restrict__ lb0,
    const float* __restrict__ Wg, const float* __restrict__ bg,
    const float* __restrict__ lwg, const float* __restrict__ lbg,
    const float* __restrict__ hW, const float* __restrict__ hb,
    float* __restrict__ out) {
  __shared__ float P[16][88];
  __shared__ float Z[16][32];
  const int tid = threadIdx.x;
  for (int i = tid; i < 16 * 88; i += 512) {
    int g = i / 88, c = i - g * 88;
    float v;
    if (c < 64) {
      float cnt = fmaxf((float)(gstart[g + 1] - gstart[g]), 1.0f);
      v = psum[g * 64 + c] / cnt;
    } else {
      v = gf[g * GDIM + (c - 64)];
    }
    P[g][c] = v;
  }
  __syncthreads();
  const int g = tid >> 5, c = tid & 31;
  float acc = b0[c];
  for (int k = 0; k < 88; ++k) acc = fmaf(P[g][k], W0[k * 32 + c], acc);
  float z = ln32(gelu_exact(acc), lw0[c], lb0[c]);
  for (int l = 0; l < LL; ++l) {
    Z[g][c] = z;
    __syncthreads();
    float a2 = bg[l * 32 + c];
    const float* Wl = Wg + l * 32 * 32;
    for (int k = 0; k < 32; ++k) a2 = fmaf(Z[g][k], Wl[k * 32 + c], a2);
    __syncthreads();
    z = ln32(gelu_exact(a2), lwg[l * 32 + c], lbg[l * 32 + c]) + z;
  }
  Z[g][c] = z * hW[c];
  __syncthreads();
  if (c == 0) {
    float s = 0.f;
    for (int k = 0; k < 32; ++k) s += Z[g][k];
    out[g] = s + hb[0];
  }
}

extern "C" void kernel_launch(void* const* d_in, const int* in_sizes, int n_in,
                              void* d_out, int out_size, void* d_ws, size_t ws_size,
                              hipStream_t stream) {
  const float* x   = (const float*)d_in[0];
  const int*   ei  = (const int*)d_in[1];
  const int* batch = (const int*)d_in[2];
  const float* gf  = (const float*)d_in[3];
  const float* W0  = (const float*)d_in[4];
  const float* as0 = (const float*)d_in[5];
  const float* ad0 = (const float*)d_in[6];
  const float* b0  = (const float*)d_in[7];
  const float* gw0 = (const float*)d_in[8];
  const float* gb0 = (const float*)d_in[9];
  const float* gm0 = (const float*)d_in[10];
  const float* Wg  = (const float*)d_in[11];
  const float* asg = (const float*)d_in[12];
  const float* adg = (const float*)d_in[13];
  const float* bg  = (const float*)d_in[14];
  const float* gwg = (const float*)d_in[15];
  const float* gbg = (const float*)d_in[16];
  const float* gmg = (const float*)d_in[17];
  const float* mW0 = (const float*)d_in[18];
  const float* mb0 = (const float*)d_in[19];
  const float* lw0 = (const float*)d_in[20];
  const float* lb0 = (const float*)d_in[21];
  const float* mWg = (const float*)d_in[22];
  const float* mbg = (const float*)d_in[23];
  const float* lwg = (const float*)d_in[24];
  const float* lbg = (const float*)d_in[25];
  const float* hW  = (const float*)d_in[26];
  const float* hb  = (const float*)d_in[27];
  float* out = (float*)d_out;
  const int* src = ei;
  const int* dst = ei + N_EDGES;

  char* p = (char*)d_ws;
  auto alloc = [&](size_t bytes) {
    char* r = p;
    p += (bytes + 255) & ~(size_t)255;
    return (void*)r;
  };
  float* X  = (float*)alloc((size_t)N_NODES * 64 * 4);
  float* T  = (float*)alloc((size_t)N_NODES * 64 * 4);
  float* F  = (float*)alloc((size_t)N_NODES * 64 * 4);
  float* ES = (float*)alloc((size_t)N_NODES * 4 * 4);
  float* ED = (float*)alloc((size_t)N_NODES * 4 * 4);
  int* ssrc = (int*)alloc((size_t)N_EDGES * 4);
  int* deg  = (int*)alloc((size_t)N_NODES * 4);
  int* off  = (int*)alloc((size_t)(N_NODES + 1) * 4);
  int* cur  = (int*)alloc((size_t)N_NODES * 4);
  int* bsum = (int*)alloc(4096);
  int* gstart = (int*)alloc((N_GRAPHS + 1) * 4);
  float* S  = (float*)alloc(N_GRAPHS * 64 * 4);
  float* SQ = (float*)alloc(N_GRAPHS * 64 * 4);
  float* MM = (float*)alloc(N_GRAPHS * 64 * 4);
  float* IS = (float*)alloc(N_GRAPHS * 64 * 4);
  (void)ws_size; (void)in_sizes; (void)n_in; (void)out_size;

  const int NB = (N_NODES + 255) / 256;
  hipMemsetAsync(deg, 0, (size_t)N_NODES * 4, stream);
  k_count_deg<<<(N_EDGES + 255) / 256, 256, 0, stream>>>(dst, deg);
  k_block_sums<<<NB, 256, 0, stream>>>(deg, bsum);
  k_scan_bsums<<<1, 512, 0, stream>>>(bsum, NB, off);
  k_scan_final<<<NB, 256, 0, stream>>>(deg, bsum, off, cur);
  k_scatter<<<(N_EDGES + 255) / 256, 256, 0, stream>>>(src, dst, cur, ssrc);
  k_graph_starts<<<1, 32, 0, stream>>>(batch, gstart);

  const int GB = (N_NODES + 127) / 128;  // 782
  for (int l = 0; l < 1 + GL; ++l) {
    const float* Xin = (l == 0) ? x : X;
    const int K = (l == 0) ? IN_DIM : 64;
    const float* Wl  = (l == 0) ? W0  : (Wg  + (size_t)(l - 1) * 64 * 64);
    const float* asl = (l == 0) ? as0 : (asg + (size_t)(l - 1) * 64);
    const float* adl = (l == 0) ? ad0 : (adg + (size_t)(l - 1) * 64);
    const float* bl  = (l == 0) ? b0  : (bg  + (size_t)(l - 1) * 64);
    const float* gwl = (l == 0) ? gw0 : (gwg + (size_t)(l - 1) * 64);
    const float* gbl = (l == 0) ? gb0 : (gbg + (size_t)(l - 1) * 64);
    const float* gml = (l == 0) ? gm0 : (gmg + (size_t)(l - 1) * 64);
    k_gemm_logits<<<GB, 128, 0, stream>>>(Xin, K, Wl, asl, adl, T, ES, ED);
    k_edge_agg<<<N_NODES / 4, 256, 0, stream>>>(T, ES, ED, off, ssrc, bl, F);
    hipMemsetAsync(S, 0, (size_t)N_GRAPHS * 64 * 4 * 2, stream);
    k_graph_moments<<<dim3(N_GRAPHS, 8), 256, 0, stream>>>(F, gstart, S, SQ);
    k_graph_stats<<<1, 1024, 0, stream>>>(S, SQ, gstart, gml, MM, IS);
    k_norm_res<<<(N_NODES * 64) / 1024, 256, 0, stream>>>(F, batch, MM, IS, gwl, gbl, X, l > 0);
  }

  hipMemsetAsync(S, 0, (size_t)N_GRAPHS * 64 * 4 * 2, stream);
  k_graph_moments<<<dim3(N_GRAPHS, 8), 256, 0, stream>>>(X, gstart, S, SQ);
  k_mlp<<<1, 512, 0, stream>>>(S, gstart, gf, mW0, mb0, lw0, lb0,
                               mWg, mbg, lwg, lbg, hW, hb, out);
}

// Round 3
// 1385.736 us; speedup vs baseline: 1.2794x; 1.1552x over previous
//
#include <hip/hip_runtime.h>
#include <math.h>

#define N_NODES 100000
#define N_EDGES 1200000
#define N_GRAPHS 16
#define CH 64
#define HEADS 4
#define GL 6
#define IN_DIM 261
#define GDIM 24
#define LIN 32
#define LL 3
#define EPSN 1e-5f

__device__ __forceinline__ float gelu_exact(float x) {
  return 0.5f * x * (1.0f + erff(x * 0.70710678118654752440f));
}

__device__ __forceinline__ float ln32(float x, float w, float b) {
  float m = x;
  m += __shfl_xor(m, 1); m += __shfl_xor(m, 2); m += __shfl_xor(m, 4);
  m += __shfl_xor(m, 8); m += __shfl_xor(m, 16);
  m *= (1.0f / 32.0f);
  float d = x - m;
  float v = d * d;
  v += __shfl_xor(v, 1); v += __shfl_xor(v, 2); v += __shfl_xor(v, 4);
  v += __shfl_xor(v, 8); v += __shfl_xor(v, 16);
  v *= (1.0f / 32.0f);
  return d * rsqrtf(v + EPSN) * w + b;
}

// ---------------- setup: CSR build (sort edges by dst) ----------------
__global__ void k_count_deg(const int* __restrict__ dst, int* __restrict__ deg) {
  int e = blockIdx.x * 256 + threadIdx.x;
  if (e < N_EDGES) atomicAdd(&deg[dst[e]], 1);
}

__global__ void k_block_sums(const int* __restrict__ deg, int* __restrict__ bsum) {
  __shared__ int sh[256];
  int i = blockIdx.x * 256 + threadIdx.x;
  sh[threadIdx.x] = (i < N_NODES) ? deg[i] : 0;
  __syncthreads();
  for (int s = 128; s > 0; s >>= 1) {
    if (threadIdx.x < s) sh[threadIdx.x] += sh[threadIdx.x + s];
    __syncthreads();
  }
  if (threadIdx.x == 0) bsum[blockIdx.x] = sh[0];
}

__global__ void k_scan_bsums(int* __restrict__ bsum, int nb, int* __restrict__ off) {
  __shared__ int sh[512];
  int i = threadIdx.x;
  int v = (i < nb) ? bsum[i] : 0;
  sh[i] = v;
  __syncthreads();
  for (int s = 1; s < 512; s <<= 1) {
    int t = (i >= s) ? sh[i - s] : 0;
    __syncthreads();
    sh[i] += t;
    __syncthreads();
  }
  if (i < nb) bsum[i] = sh[i] - v;
  if (i == nb - 1) off[N_NODES] = sh[i];
}

__global__ void k_scan_final(const int* __restrict__ deg, const int* __restrict__ bsum,
                             int* __restrict__ off, int* __restrict__ cur) {
  __shared__ int sh[256];
  int i = blockIdx.x * 256 + threadIdx.x;
  int v = (i < N_NODES) ? deg[i] : 0;
  sh[threadIdx.x] = v;
  __syncthreads();
  for (int s = 1; s < 256; s <<= 1) {
    int t = (threadIdx.x >= s) ? sh[threadIdx.x - s] : 0;
    __syncthreads();
    sh[threadIdx.x] += t;
    __syncthreads();
  }
  if (i < N_NODES) {
    int ex = bsum[blockIdx.x] + sh[threadIdx.x] - v;
    off[i] = ex;
    cur[i] = ex;
  }
}

__global__ void k_scatter(const int* __restrict__ src, const int* __restrict__ dst,
                          int* __restrict__ cur, int* __restrict__ ssrc) {
  int e = blockIdx.x * 256 + threadIdx.x;
  if (e < N_EDGES) {
    int p = atomicAdd(&cur[dst[e]], 1);
    ssrc[p] = src[e];
  }
}

__global__ void k_graph_starts(const int* __restrict__ batch, int* __restrict__ gstart) {
  int g = threadIdx.x;
  if (g > N_GRAPHS) return;
  int lo = 0, hi = N_NODES;
  while (lo < hi) {
    int mid = (lo + hi) >> 1;
    if (batch[mid] < g) lo = mid + 1; else hi = mid;
  }
  gstart[g] = lo;
}

// ---------------- per-layer: GEMM (t = X @ W) + attention logits ----------------
// 256 threads, tile 64 rows x 64 cols, per-thread 4x4. X kept [row][k] (no transpose).
__global__ __launch_bounds__(256) void k_gemm_logits(
    const float* __restrict__ Xin, int K, const float* __restrict__ W,
    const float* __restrict__ a_src, const float* __restrict__ a_dst,
    float* __restrict__ T, float* __restrict__ ES, float* __restrict__ ED) {
  __shared__ float sX[64][68];  // [row][k], pad 4: 16B-aligned rows, 2-way reads only
  __shared__ float sW[64][68];  // [k][col]
  const int tid = threadIdx.x;
  const int rg = tid >> 4;      // 0..15 -> rows rg*4..+3
  const int cg = tid & 15;      // 0..15 -> cols cg*4..+3
  const long r0 = (long)blockIdx.x * 64;
  float acc[4][4];
  #pragma unroll
  for (int i = 0; i < 4; ++i)
    #pragma unroll
    for (int j = 0; j < 4; ++j) acc[i][j] = 0.f;

  for (int kc = 0; kc < K; kc += 64) {
    const int kl = min(64, K - kc);
    // --- stage W chunk [kl][64], zero-pad k>=kl ---
    #pragma unroll
    for (int t = 0; t < 4; ++t) {
      int j = tid + (t << 8);
      int k = j >> 4, c4 = (j & 15) << 2;
      float4 v = make_float4(0.f, 0.f, 0.f, 0.f);
      if (k < kl) v = *(const float4*)(W + (size_t)(kc + k) * 64 + c4);
      *(float4*)&sW[k][c4] = v;
    }
    // --- stage X chunk [64 rows][kl], identity layout ---
    if (K == 64) {
      #pragma unroll
      for (int t = 0; t < 4; ++t) {
        int j = tid + (t << 8);
        int row = j >> 4, k4 = (j & 15) << 2;
        float4 v = make_float4(0.f, 0.f, 0.f, 0.f);
        if (r0 + row < N_NODES) v = *(const float4*)(Xin + (r0 + row) * 64 + k4);
        *(float4*)&sX[row][k4] = v;
      }
    } else {
      for (int i = tid; i < 64 * 64; i += 256) {
        int row = i >> 6, k = i & 63;
        float v = 0.f;
        if (k < kl && r0 + row < N_NODES) v = Xin[(r0 + row) * (long)K + kc + k];
        sX[row][k] = v;
      }
    }
    __syncthreads();
    // --- FMA: per k4 step, 8 b128 reads -> 64 FMA ---
    const int klim = (kl + 3) & ~3;
    #pragma unroll 4
    for (int k4 = 0; k4 < klim; k4 += 4) {
      float4 x0 = *(const float4*)&sX[rg * 4 + 0][k4];
      float4 x1 = *(const float4*)&sX[rg * 4 + 1][k4];
      float4 x2 = *(const float4*)&sX[rg * 4 + 2][k4];
      float4 x3 = *(const float4*)&sX[rg * 4 + 3][k4];
      float4 w0 = *(const float4*)&sW[k4 + 0][cg * 4];
      float4 w1 = *(const float4*)&sW[k4 + 1][cg * 4];
      float4 w2 = *(const float4*)&sW[k4 + 2][cg * 4];
      float4 w3 = *(const float4*)&sW[k4 + 3][cg * 4];
      float xr[4][4] = {{x0.x, x0.y, x0.z, x0.w},
                        {x1.x, x1.y, x1.z, x1.w},
                        {x2.x, x2.y, x2.z, x2.w},
                        {x3.x, x3.y, x3.z, x3.w}};
      float wr[4][4] = {{w0.x, w0.y, w0.z, w0.w},
                        {w1.x, w1.y, w1.z, w1.w},
                        {w2.x, w2.y, w2.z, w2.w},
                        {w3.x, w3.y, w3.z, w3.w}};
      #pragma unroll
      for (int p = 0; p < 4; ++p)
        #pragma unroll
        for (int i = 0; i < 4; ++i)
          #pragma unroll
          for (int j = 0; j < 4; ++j)
            acc[i][j] = fmaf(xr[i][p], wr[p][j], acc[i][j]);
    }
    __syncthreads();
  }

  // --- epilogue: store T, per-head logit sums (4 cols per thread, one head) ---
  const int c0 = cg * 4;
  const int h = cg >> 2;      // head of this 4-col island
  float as[4], ad[4];
  #pragma unroll
  for (int j = 0; j < 4; ++j) {
    as[j] = a_src[c0 + j];
    ad[j] = a_dst[c0 + j];
  }
  #pragma unroll
  for (int i = 0; i < 4; ++i) {
    const long row = r0 + rg * 4 + i;
    if (row >= N_NODES) continue;   // uniform across the 4 reducing lanes (same rg)
    *(float4*)(T + row * 64 + c0) = make_float4(acc[i][0], acc[i][1], acc[i][2], acc[i][3]);
    float vs = 0.f, vd = 0.f;
    #pragma unroll
    for (int j = 0; j < 4; ++j) {
      vs = fmaf(acc[i][j], as[j], vs);
      vd = fmaf(acc[i][j], ad[j], vd);
    }
    vs += __shfl_xor(vs, 1); vs += __shfl_xor(vs, 2);
    vd += __shfl_xor(vd, 1); vd += __shfl_xor(vd, 2);
    if ((cg & 3) == 0) {
      ES[row * 4 + h] = vs;
      ED[row * 4 + h] = vd;
    }
  }
}

// ---------------- per-layer: edge softmax + aggregate (wave per node) ----------------
__global__ __launch_bounds__(256) void k_edge_agg(
    const float* __restrict__ T, const float* __restrict__ ES, const float* __restrict__ ED,
    const int* __restrict__ off, const int* __restrict__ ssrc,
    const float* __restrict__ bias, float* __restrict__ F) {
  const int lane = threadIdx.x & 63;
  const int n = blockIdx.x * 4 + (threadIdx.x >> 6);
  if (n >= N_NODES) return;
  const int e0 = off[n];
  const int ec = off[n + 1] - e0;
  const int hd = lane & 3;    // phase-A head (lane = edge*4 + head)
  const int qh = lane >> 4;   // phase-B head (lane = channel)
  const float ed_h = ED[n * 4 + hd];
  float x0 = ES[n * 4 + hd] + ed_h;
  x0 = fmaxf(x0, 0.2f * x0);                 // leaky_relu
  float m_run = x0;
  float s_run = 1.0f;
  const float* Tl = T + lane;
  float acc = Tl[(long)n * 64];              // self message
  for (int base = 0; base < ec; base += 16) {
    const int eidx = base + (lane >> 2);
    const bool valid = eidx < ec;
    const int sv = valid ? ssrc[e0 + eidx] : n;
    float v = ES[sv * 4 + hd] + ed_h;
    float logit = valid ? fmaxf(v, 0.2f * v) : -1e30f;
    float cm = logit;
    cm = fmaxf(cm, __shfl_xor(cm, 4));
    cm = fmaxf(cm, __shfl_xor(cm, 8));
    cm = fmaxf(cm, __shfl_xor(cm, 16));
    cm = fmaxf(cm, __shfl_xor(cm, 32));
    const float new_m = fmaxf(m_run, cm);
    const float scale = __expf(m_run - new_m);
    const float p = valid ? __expf(logit - new_m) : 0.f;
    float ps = p;
    ps += __shfl_xor(ps, 4); ps += __shfl_xor(ps, 8);
    ps += __shfl_xor(ps, 16); ps += __shfl_xor(ps, 32);
    s_run = fmaf(s_run, scale, ps);
    m_run = new_m;
    acc *= __shfl(scale, qh);
    int rows[16];
    float al[16], tv[16];
    #pragma unroll
    for (int e = 0; e < 16; ++e) rows[e] = __shfl(sv, e << 2);
    #pragma unroll
    for (int e = 0; e < 16; ++e) al[e] = __shfl(p, (e << 2) | qh);
    #pragma unroll
    for (int e = 0; e < 16; ++e) tv[e] = Tl[(long)rows[e] * 64];
    #pragma unroll
    for (int e = 0; e < 16; ++e) acc = fmaf(al[e], tv[e], acc);
  }
  const float s_q = __shfl(s_run, qh);
  const float o = acc / (s_q + 1e-16f) + bias[lane];
  F[(long)n * 64 + lane] = gelu_exact(o);
}

// ---------------- GraphNorm ----------------
__global__ void k_graph_moments(const float* __restrict__ F, const int* __restrict__ gstart,
                                float* __restrict__ S, float* __restrict__ SQ) {
  const int g = blockIdx.x;
  const int s0 = gstart[g];
  const int rows = gstart[g + 1] - s0;
  const int lane = threadIdx.x & 63;
  const int w = threadIdx.x >> 6;
  float sum = 0.f, sq = 0.f;
  for (int r = blockIdx.y * 4 + w; r < rows; r += gridDim.y * 4) {
    float v = F[(long)(s0 + r) * 64 + lane];
    sum += v;
    sq = fmaf(v, v, sq);
  }
  __shared__ float ls[4][64];
  __shared__ float lq[4][64];
  ls[w][lane] = sum;
  lq[w][lane] = sq;
  __syncthreads();
  if (w == 0) {
    float a = ls[0][lane] + ls[1][lane] + ls[2][lane] + ls[3][lane];
    float b = lq[0][lane] + lq[1][lane] + lq[2][lane] + lq[3][lane];
    atomicAdd(&S[g * 64 + lane], a);
    atomicAdd(&SQ[g * 64 + lane], b);
  }
}

__global__ void k_graph_stats(const float* __restrict__ S, const float* __restrict__ SQ,
                              const int* __restrict__ gstart, const float* __restrict__ ms,
                              float* __restrict__ MM, float* __restrict__ IS) {
  const int i = threadIdx.x;
  const int g = i >> 6, c = i & 63;
  const float cnt = fmaxf((float)(gstart[g + 1] - gstart[g]), 1.0f);
  const float mean = S[i] / cnt;
  const float mm = mean * ms[c];
  float var = SQ[i] / cnt - 2.f * mm * mean + mm * mm;
  MM[i] = mm;
  IS[i] = rsqrtf(fmaxf(var, 0.f) + EPSN);
}

__global__ void k_norm_res(const float* __restrict__ F, const int* __restrict__ batch,
                           const float* __restrict__ MM, const float* __restrict__ IS,
                           const float* __restrict__ w, const float* __restrict__ b,
                           float* __restrict__ X, int residual) {
  const long i4 = (long)blockIdx.x * 256 + threadIdx.x;   // float4 index
  const int n = (int)(i4 >> 4);
  const int c4 = (int)(i4 & 15) << 2;
  const int g = batch[n];
  float4 f = *(const float4*)(F + i4 * 4);
  float4 mm = *(const float4*)(MM + g * 64 + c4);
  float4 is = *(const float4*)(IS + g * 64 + c4);
  float4 wv = *(const float4*)(w + c4);
  float4 bv = *(const float4*)(b + c4);
  float4 y;
  y.x = fmaf(wv.x * (f.x - mm.x), is.x, bv.x);
  y.y = fmaf(wv.y * (f.y - mm.y), is.y, bv.y);
  y.z = fmaf(wv.z * (f.z - mm.z), is.z, bv.z);
  y.w = fmaf(wv.w * (f.w - mm.w), is.w, bv.w);
  float4* xp = (float4*)(X + i4 * 4);
  if (residual) {
    float4 xo = *xp;
    y.x += xo.x; y.y += xo.y; y.z += xo.z; y.w += xo.w;
  }
  *xp = y;
}

// ---------------- pooled MLP head (one block) ----------------
__global__ __launch_bounds__(512) void k_mlp(
    const float* __restrict__ psum, const int* __restrict__ gstart, const float* __restrict__ gf,
    const float* __restrict__ W0, const float* __restrict__ b0,
    const float* __restrict__ lw0, const float* __restrict__ lb0,
    const float* __restrict__ Wg, const float* __restrict__ bg,
    const float* __restrict__ lwg, const float* __restrict__ lbg,
    const float* __restrict__ hW, const float* __restrict__ hb,
    float* __restrict__ out) {
  __shared__ float P[16][88];
  __shared__ float Z[16][32];
  const int tid = threadIdx.x;
  for (int i = tid; i < 16 * 88; i += 512) {
    int g = i / 88, c = i - g * 88;
    float v;
    if (c < 64) {
      float cnt = fmaxf((float)(gstart[g + 1] - gstart[g]), 1.0f);
      v = psum[g * 64 + c] / cnt;
    } else {
      v = gf[g * GDIM + (c - 64)];
    }
    P[g][c] = v;
  }
  __syncthreads();
  const int g = tid >> 5, c = tid & 31;
  float acc = b0[c];
  for (int k = 0; k < 88; ++k) acc = fmaf(P[g][k], W0[k * 32 + c], acc);
  float z = ln32(gelu_exact(acc), lw0[c], lb0[c]);
  for (int l = 0; l < LL; ++l) {
    Z[g][c] = z;
    __syncthreads();
    float a2 = bg[l * 32 + c];
    const float* Wl = Wg + l * 32 * 32;
    for (int k = 0; k < 32; ++k) a2 = fmaf(Z[g][k], Wl[k * 32 + c], a2);
    __syncthreads();
    z = ln32(gelu_exact(a2), lwg[l * 32 + c], lbg[l * 32 + c]) + z;
  }
  Z[g][c] = z * hW[c];
  __syncthreads();
  if (c == 0) {
    float s = 0.f;
    for (int k = 0; k < 32; ++k) s += Z[g][k];
    out[g] = s + hb[0];
  }
}

extern "C" void kernel_launch(void* const* d_in, const int* in_sizes, int n_in,
                              void* d_out, int out_size, void* d_ws, size_t ws_size,
                              hipStream_t stream) {
  const float* x   = (const float*)d_in[0];
  const int*   ei  = (const int*)d_in[1];
  const int* batch = (const int*)d_in[2];
  const float* gf  = (const float*)d_in[3];
  const float* W0  = (const float*)d_in[4];
  const float* as0 = (const float*)d_in[5];
  const float* ad0 = (const float*)d_in[6];
  const float* b0  = (const float*)d_in[7];
  const float* gw0 = (const float*)d_in[8];
  const float* gb0 = (const float*)d_in[9];
  const float* gm0 = (const float*)d_in[10];
  const float* Wg  = (const float*)d_in[11];
  const float* asg = (const float*)d_in[12];
  const float* adg = (const float*)d_in[13];
  const float* bg  = (const float*)d_in[14];
  const float* gwg = (const float*)d_in[15];
  const float* gbg = (const float*)d_in[16];
  const float* gmg = (const float*)d_in[17];
  const float* mW0 = (const float*)d_in[18];
  const float* mb0 = (const float*)d_in[19];
  const float* lw0 = (const float*)d_in[20];
  const float* lb0 = (const float*)d_in[21];
  const float* mWg = (const float*)d_in[22];
  const float* mbg = (const float*)d_in[23];
  const float* lwg = (const float*)d_in[24];
  const float* lbg = (const float*)d_in[25];
  const float* hW  = (const float*)d_in[26];
  const float* hb  = (const float*)d_in[27];
  float* out = (float*)d_out;
  const int* src = ei;
  const int* dst = ei + N_EDGES;

  char* p = (char*)d_ws;
  auto alloc = [&](size_t bytes) {
    char* r = p;
    p += (bytes + 255) & ~(size_t)255;
    return (void*)r;
  };
  float* X  = (float*)alloc((size_t)N_NODES * 64 * 4);
  float* T  = (float*)alloc((size_t)N_NODES * 64 * 4);
  float* F  = (float*)alloc((size_t)N_NODES * 64 * 4);
  float* ES = (float*)alloc((size_t)N_NODES * 4 * 4);
  float* ED = (float*)alloc((size_t)N_NODES * 4 * 4);
  int* ssrc = (int*)alloc((size_t)N_EDGES * 4);
  int* deg  = (int*)alloc((size_t)N_NODES * 4);
  int* off  = (int*)alloc((size_t)(N_NODES + 1) * 4);
  int* cur  = (int*)alloc((size_t)N_NODES * 4);
  int* bsum = (int*)alloc(4096);
  int* gstart = (int*)alloc((N_GRAPHS + 1) * 4);
  float* S  = (float*)alloc(N_GRAPHS * 64 * 4);
  float* SQ = (float*)alloc(N_GRAPHS * 64 * 4);
  float* MM = (float*)alloc(N_GRAPHS * 64 * 4);
  float* IS = (float*)alloc(N_GRAPHS * 64 * 4);
  (void)ws_size; (void)in_sizes; (void)n_in; (void)out_size;

  const int NB = (N_NODES + 255) / 256;
  hipMemsetAsync(deg, 0, (size_t)N_NODES * 4, stream);
  k_count_deg<<<(N_EDGES + 255) / 256, 256, 0, stream>>>(dst, deg);
  k_block_sums<<<NB, 256, 0, stream>>>(deg, bsum);
  k_scan_bsums<<<1, 512, 0, stream>>>(bsum, NB, off);
  k_scan_final<<<NB, 256, 0, stream>>>(deg, bsum, off, cur);
  k_scatter<<<(N_EDGES + 255) / 256, 256, 0, stream>>>(src, dst, cur, ssrc);
  k_graph_starts<<<1, 32, 0, stream>>>(batch, gstart);

  const int GB = (N_NODES + 63) / 64;  // 1563
  for (int l = 0; l < 1 + GL; ++l) {
    const float* Xin = (l == 0) ? x : X;
    const int K = (l == 0) ? IN_DIM : 64;
    const float* Wl  = (l == 0) ? W0  : (Wg  + (size_t)(l - 1) * 64 * 64);
    const float* asl = (l == 0) ? as0 : (asg + (size_t)(l - 1) * 64);
    const float* adl = (l == 0) ? ad0 : (adg + (size_t)(l - 1) * 64);
    const float* bl  = (l == 0) ? b0  : (bg  + (size_t)(l - 1) * 64);
    const float* gwl = (l == 0) ? gw0 : (gwg + (size_t)(l - 1) * 64);
    const float* gbl = (l == 0) ? gb0 : (gbg + (size_t)(l - 1) * 64);
    const float* gml = (l == 0) ? gm0 : (gmg + (size_t)(l - 1) * 64);
    k_gemm_logits<<<GB, 256, 0, stream>>>(Xin, K, Wl, asl, adl, T, ES, ED);
    k_edge_agg<<<N_NODES / 4, 256, 0, stream>>>(T, ES, ED, off, ssrc, bl, F);
    hipMemsetAsync(S, 0, (size_t)N_GRAPHS * 64 * 4 * 2, stream);
    k_graph_moments<<<dim3(N_GRAPHS, 8), 256, 0, stream>>>(F, gstart, S, SQ);
    k_graph_stats<<<1, 1024, 0, stream>>>(S, SQ, gstart, gml, MM, IS);
    k_norm_res<<<(N_NODES * 64) / 1024, 256, 0, stream>>>(F, batch, MM, IS, gwl, gbl, X, l > 0);
  }

  hipMemsetAsync(S, 0, (size_t)N_GRAPHS * 64 * 4 * 2, stream);
  k_graph_moments<<<dim3(N_GRAPHS, 8), 256, 0, stream>>>(X, gstart, S, SQ);
  k_mlp<<<1, 512, 0, stream>>>(S, gstart, gf, mW0, mb0, lw0, lb0,
                               mWg, mbg, lwg, lbg, hW, hb, out);
}